// Round 13
// baseline (452.107 us; speedup 1.0000x reference)
//
#include <hip/hip_runtime.h>
#include <math.h>

// Problem dims
#define S_LEN 2048
#define D_HEAD 64
#define BH 32
#define ROWS 16

typedef __attribute__((ext_vector_type(8))) short short8;    // 8 bf16 (4 VGPR)
typedef __attribute__((ext_vector_type(4))) short short4v;   // 8B LDS chunk
typedef __attribute__((ext_vector_type(4))) float f32x4;

// LDS row stride in bf16 elems: 4104B rows -> 8B aligned, +2-bank row shift
#define SPAD 2052

__device__ __forceinline__ short f2bf(float f) {
  union { float f; unsigned u; } a; a.f = f;
  unsigned u = a.u;
  unsigned r = (u + 0x7fffu + ((u >> 16) & 1u)) >> 16;   // RNE, no NaNs here
  return (short)r;
}
__device__ __forceinline__ float bf2f(unsigned short h) {
  union { unsigned u; float f; } a; a.u = ((unsigned)h) << 16; return a.f;
}
__device__ __forceinline__ f32x4 ntl4(const float* p) { return __builtin_nontemporal_load((const f32x4*)p); }
__device__ __forceinline__ void  nts4(float* p, f32x4 v) { __builtin_nontemporal_store(v, (f32x4*)p); }

// ---------------------------------------------------------------------------
// Kernel T: K [bh][64][2048] -> kT [bh][2048][64] bf16 ; V [bh][2048][64] ->
// vT [bh][64][2048] bf16. Fully coalesced both sides.
// ---------------------------------------------------------------------------
__global__ __launch_bounds__(256) void transpose_kernel(
    const float* __restrict__ kin, const float* __restrict__ vin,
    unsigned short* __restrict__ kT, unsigned short* __restrict__ vT)
{
  __shared__ float tile[64][65];
  const int bh = blockIdx.y;
  const int bx = blockIdx.x;
  const int t  = threadIdx.x;

  if (blockIdx.z == 0) {
    const float* in = kin + (size_t)bh * D_HEAD * S_LEN;
    #pragma unroll
    for (int p = 0; p < 4; ++p) {
      const int row = p * 16 + (t >> 4);
      f32x4 f = ntl4(in + (size_t)row * S_LEN + bx * 64 + (t & 15) * 4);
      tile[row][(t & 15) * 4 + 0] = f.x; tile[row][(t & 15) * 4 + 1] = f.y;
      tile[row][(t & 15) * 4 + 2] = f.z; tile[row][(t & 15) * 4 + 3] = f.w;
    }
    __syncthreads();
    union { unsigned short h[16]; uint4 q[2]; } u;
    #pragma unroll
    for (int i = 0; i < 16; ++i) u.h[i] = (unsigned short)f2bf(tile[(t & 3) * 16 + i][t >> 2]);
    uint4* dst = (uint4*)(kT + (size_t)bh * S_LEN * D_HEAD
                             + (size_t)(bx * 64 + (t >> 2)) * D_HEAD + (t & 3) * 16);
    dst[0] = u.q[0]; dst[1] = u.q[1];
  } else {
    const float* in = vin + (size_t)bh * S_LEN * D_HEAD;
    #pragma unroll
    for (int p = 0; p < 4; ++p) {
      const int row = p * 16 + (t >> 4);
      f32x4 f = ntl4(in + (size_t)(bx * 64 + row) * D_HEAD + (t & 15) * 4);
      tile[row][(t & 15) * 4 + 0] = f.x; tile[row][(t & 15) * 4 + 1] = f.y;
      tile[row][(t & 15) * 4 + 2] = f.z; tile[row][(t & 15) * 4 + 3] = f.w;
    }
    __syncthreads();
    union { unsigned short h[16]; uint4 q[2]; } u;
    #pragma unroll
    for (int i = 0; i < 16; ++i) u.h[i] = (unsigned short)f2bf(tile[(t & 3) * 16 + i][t >> 2]);
    uint4* dst = (uint4*)(vT + (size_t)bh * D_HEAD * S_LEN
                             + (size_t)(t >> 2) * S_LEN + bx * 64 + (t & 3) * 16);
    dst[0] = u.q[0]; dst[1] = u.q[1];
  }
}

// ---------------------------------------------------------------------------
// Fused kernel, column-halves pipeline (A = cols 0..1023, B = 1024..2047):
//  pre : 16-deep prev(A) prefetch
//  P1A : QK^T half A -> LDS
//  bar
//  P2A ∥ P1B: consume prev(A) / issue prev(B) / scores(A) store / e(A)->LDS,
//             one P1(B) MFMA tile interleaved per 4 chunks
//  bar
//  P2B ∥ PVA: consume prev(B) / scores(B) store / e(B)->LDS, one PV(A) MFMA
//             iter per 2 chunks (PV uses unnormalized e; no rl needed)
//  rowsum reduce -> rl (in-register for the row owner)
//  bar
//  WST ∥ PVB: weights = e*rl store (32 chunks) ∥ PV(B) MFMA
//  bar; merge 4 waves' partial O via LDS alias, scale by rl, NT store.
// Every barrier interval has HBM traffic in flight + L2/MFMA work to hide it.
// ---------------------------------------------------------------------------
__global__ __launch_bounds__(256, 2) void fused_kernel(
    const float* __restrict__ q, const unsigned short* __restrict__ kT,
    const float* __restrict__ prev, const float* __restrict__ scale_p,
    const unsigned short* __restrict__ vT,
    float* __restrict__ scores, float* __restrict__ weights, float* __restrict__ outO)
{
  __shared__ union {
    unsigned short s[ROWS][SPAD];   // 65664 B
    float om[4][ROWS][68];          // aliased after final barrier
  } sh;

  const int bh   = blockIdx.y;
  const int m0   = blockIdx.x * ROWS;
  const int tid  = threadIdx.x;
  const int w    = tid >> 6;
  const int lane = tid & 63;
  const int lr   = lane & 15;
  const int lg   = lane >> 4;
  const float scale = scale_p[0];

  // P2 mapping: row owned by an aligned 16-lane group of one wave
  const int row = tid >> 4;          // 0..15
  const int cq  = (tid & 15) * 4;    // 0..60
  const size_t rowoff = (size_t)bh * S_LEN * S_LEN + (size_t)(m0 + row) * S_LEN;
  const float* prevrow = prev + rowoff;

  // ---- deep prefetch: half A (cols 0..1023 of this thread's row) ----
  f32x4 pf[16];
  #pragma unroll
  for (int u = 0; u < 16; ++u) pf[u] = ntl4(prevrow + cq + u * 64);

  // Q A-frags: row = m0+lr, d = kk*32 + lg*8 + j
  short8 aq[2];
  {
    const float* qrow = q + ((size_t)bh * S_LEN + m0 + lr) * D_HEAD;
    #pragma unroll
    for (int kk = 0; kk < 2; ++kk) {
      f32x4 f0 = *(const f32x4*)(qrow + kk * 32 + lg * 8);
      f32x4 f1 = *(const f32x4*)(qrow + kk * 32 + lg * 8 + 4);
      short8 a;
      a[0]=f2bf(f0.x); a[1]=f2bf(f0.y); a[2]=f2bf(f0.z); a[3]=f2bf(f0.w);
      a[4]=f2bf(f1.x); a[5]=f2bf(f1.y); a[6]=f2bf(f1.z); a[7]=f2bf(f1.w);
      aq[kk] = a;
    }
  }

  const unsigned short* kbase = kT + (size_t)bh * S_LEN * D_HEAD;
  const unsigned short* vbase = vT + (size_t)bh * D_HEAD * S_LEN;
  float* srow = scores + rowoff;

  // one QK^T 64-col tile -> LDS
  auto p1_tile = [&](int n0) {
    f32x4 acc[4];
    #pragma unroll
    for (int nt = 0; nt < 4; ++nt) acc[nt] = (f32x4){0.f, 0.f, 0.f, 0.f};
    #pragma unroll
    for (int kk = 0; kk < 2; ++kk) {
      #pragma unroll
      for (int nt = 0; nt < 4; ++nt) {
        const short8 b = *(const short8*)(
            kbase + (size_t)(n0 + nt * 16 + lr) * D_HEAD + kk * 32 + lg * 8);
        acc[nt] = __builtin_amdgcn_mfma_f32_16x16x32_bf16(aq[kk], b, acc[nt], 0, 0, 0);
      }
    }
    #pragma unroll
    for (int nt = 0; nt < 4; ++nt)
      #pragma unroll
      for (int rg = 0; rg < 4; ++rg)
        sh.s[lg * 4 + rg][n0 + nt * 16 + lr] = (unsigned short)f2bf(acc[nt][rg]);
  };

  f32x4 accp[4];
  #pragma unroll
  for (int ct = 0; ct < 4; ++ct) accp[ct] = (f32x4){0.f, 0.f, 0.f, 0.f};

  // one PV 32-col k-step (A-frag from LDS e, B = vT via L2)
  auto pv_iter = [&](int c4) {
    short4v h0 = *(const short4v*)&sh.s[lr][c4];
    short4v h1 = *(const short4v*)&sh.s[lr][c4 + 4];
    short8 a;
    a[0]=h0[0]; a[1]=h0[1]; a[2]=h0[2]; a[3]=h0[3];
    a[4]=h1[0]; a[5]=h1[1]; a[6]=h1[2]; a[7]=h1[3];
    #pragma unroll
    for (int ct = 0; ct < 4; ++ct) {
      const short8 b = *(const short8*)(vbase + (size_t)(ct * 16 + lr) * S_LEN + c4);
      accp[ct] = __builtin_amdgcn_mfma_f32_16x16x32_bf16(a, b, accp[ct], 0, 0, 0);
    }
  };

  float sum = 0.f;

  // one P2 chunk: consume p, scores store, e -> LDS, sum
  auto p2_chunk = [&](int c, f32x4 p) {
    short4v h = *(const short4v*)&sh.s[row][c];
    f32x4 s;
    s.x = bf2f((unsigned short)h[0]) * scale + p.x;
    s.y = bf2f((unsigned short)h[1]) * scale + p.y;
    s.z = bf2f((unsigned short)h[2]) * scale + p.z;
    s.w = bf2f((unsigned short)h[3]) * scale + p.w;
    nts4(srow + c, s);
    const float e0 = __expf(s.x), e1 = __expf(s.y), e2 = __expf(s.z), e3 = __expf(s.w);
    sum += (e0 + e1) + (e2 + e3);
    short4v g;
    g[0] = f2bf(e0); g[1] = f2bf(e1); g[2] = f2bf(e2); g[3] = f2bf(e3);
    *(short4v*)&sh.s[row][c] = g;
  };

  // ---------------- P1(A) ----------------
  #pragma unroll
  for (int t8 = 0; t8 < 4; ++t8) p1_tile(w * 256 + t8 * 64);
  __syncthreads();

  // ---------------- P2(A) ∥ P1(B) ----------------
  #pragma unroll
  for (int u = 0; u < 16; ++u) {
    const f32x4 p = pf[u];
    pf[u] = ntl4(prevrow + 1024 + cq + u * 64);   // issue half-B load
    p2_chunk(cq + u * 64, p);
    if ((u & 3) == 3) p1_tile(1024 + w * 256 + (u >> 2) * 64);
  }
  __syncthreads();

  // ---------------- P2(B) ∥ PV(A) ----------------
  #pragma unroll
  for (int u = 0; u < 16; ++u) {
    p2_chunk(1024 + cq + u * 64, pf[u]);
    if (u & 1) pv_iter(w * 256 + (u >> 1) * 32 + lg * 8);
  }

  // full row-sum across the 16-lane group (same wave, aligned)
  #pragma unroll
  for (int msk = 1; msk <= 8; msk <<= 1)
    sum += __shfl_xor(sum, msk, 64);
  const float rl = 1.0f / sum;
  __syncthreads();   // e(B) in LDS complete for all rows

  // ---------------- weights store ∥ PV(B) ----------------
  float* wrow = weights + rowoff;
  #pragma unroll
  for (int i = 0; i < 8; ++i) {
    pv_iter(1024 + w * 256 + i * 32 + lg * 8);
    #pragma unroll
    for (int v = 0; v < 4; ++v) {
      const int c = cq + (i * 4 + v) * 64;
      short4v hw = *(const short4v*)&sh.s[row][c];
      f32x4 e;
      e.x = bf2f((unsigned short)hw[0]) * rl;
      e.y = bf2f((unsigned short)hw[1]) * rl;
      e.z = bf2f((unsigned short)hw[2]) * rl;
      e.w = bf2f((unsigned short)hw[3]) * rl;
      nts4(wrow + c, e);
    }
  }
  __syncthreads();   // all sh.s reads done; safe to alias sh.om

  #pragma unroll
  for (int ct = 0; ct < 4; ++ct)
    #pragma unroll
    for (int rg = 0; rg < 4; ++rg)
      sh.om[w][lg * 4 + rg][ct * 16 + lr] = accp[ct][rg];
  __syncthreads();

  {
    const int d4 = (tid & 15) * 4;
    f32x4 v;
    #pragma unroll
    for (int i = 0; i < 4; ++i)
      v[i] = (sh.om[0][row][d4 + i] + sh.om[1][row][d4 + i]
            + sh.om[2][row][d4 + i] + sh.om[3][row][d4 + i]) * rl;
    nts4(outO + ((size_t)bh * S_LEN + m0 + row) * D_HEAD + d4, v);
  }
}

// ---------------------------------------------------------------------------
extern "C" void kernel_launch(void* const* d_in, const int* in_sizes, int n_in,
                              void* d_out, int out_size, void* d_ws, size_t ws_size,
                              hipStream_t stream)
{
  const float* q     = (const float*)d_in[0];
  const float* kin   = (const float*)d_in[1];
  const float* vin   = (const float*)d_in[2];
  const float* prev  = (const float*)d_in[3];
  const float* scale = (const float*)d_in[4];

  float* O  = (float*)d_out;                                  // [32][2048][64]
  float* W  = O + (size_t)BH * S_LEN * D_HEAD;                // [32][2048][2048]
  float* Sc = W + (size_t)BH * S_LEN * S_LEN;                 // [32][2048][2048]

  unsigned short* kT = (unsigned short*)d_ws;                 // [32][2048][64] bf16
  unsigned short* vT = kT + (size_t)BH * S_LEN * D_HEAD;      // [32][64][2048] bf16

  dim3 tgrid(S_LEN / 64, BH, 2);
  hipLaunchKernelGGL(transpose_kernel, tgrid, dim3(256), 0, stream, kin, vin, kT, vT);

  dim3 grid(S_LEN / ROWS, BH);
  hipLaunchKernelGGL(fused_kernel, grid, dim3(256), 0, stream,
                     q, kT, prev, scale, vT, Sc, W, O);
}

// Round 14
// 433.428 us; speedup vs baseline: 1.0431x; 1.0431x over previous
//
#include <hip/hip_runtime.h>
#include <math.h>

// Problem dims
#define S_LEN 2048
#define D_HEAD 64
#define BH 32
#define ROWS 16

typedef __attribute__((ext_vector_type(8))) short short8;    // 8 bf16 (4 VGPR)
typedef __attribute__((ext_vector_type(4))) short short4v;   // 8B LDS chunk
typedef __attribute__((ext_vector_type(4))) float f32x4;

// LDS row stride in bf16 elems: 4104B rows -> 8B aligned, +2-bank row shift
#define SPAD 2052

__device__ __forceinline__ short f2bf(float f) {
  union { float f; unsigned u; } a; a.f = f;
  unsigned u = a.u;
  unsigned r = (u + 0x7fffu + ((u >> 16) & 1u)) >> 16;   // RNE, no NaNs here
  return (short)r;
}
__device__ __forceinline__ float bf2f(unsigned short h) {
  union { unsigned u; float f; } a; a.u = ((unsigned)h) << 16; return a.f;
}
__device__ __forceinline__ f32x4 ntl4(const float* p) { return __builtin_nontemporal_load((const f32x4*)p); }
__device__ __forceinline__ void  nts4(float* p, f32x4 v) { __builtin_nontemporal_store(v, (f32x4*)p); }

// ---------------------------------------------------------------------------
// Kernel T: K [bh][64][2048] -> kT [bh][2048][64] bf16 ; V [bh][2048][64] ->
// vT [bh][64][2048] bf16. Fully coalesced both sides.
// ---------------------------------------------------------------------------
__global__ __launch_bounds__(256) void transpose_kernel(
    const float* __restrict__ kin, const float* __restrict__ vin,
    unsigned short* __restrict__ kT, unsigned short* __restrict__ vT)
{
  __shared__ float tile[64][65];
  const int bh = blockIdx.y;
  const int bx = blockIdx.x;
  const int t  = threadIdx.x;

  if (blockIdx.z == 0) {
    const float* in = kin + (size_t)bh * D_HEAD * S_LEN;
    #pragma unroll
    for (int p = 0; p < 4; ++p) {
      const int row = p * 16 + (t >> 4);
      f32x4 f = ntl4(in + (size_t)row * S_LEN + bx * 64 + (t & 15) * 4);
      tile[row][(t & 15) * 4 + 0] = f.x; tile[row][(t & 15) * 4 + 1] = f.y;
      tile[row][(t & 15) * 4 + 2] = f.z; tile[row][(t & 15) * 4 + 3] = f.w;
    }
    __syncthreads();
    union { unsigned short h[16]; uint4 q[2]; } u;
    #pragma unroll
    for (int i = 0; i < 16; ++i) u.h[i] = (unsigned short)f2bf(tile[(t & 3) * 16 + i][t >> 2]);
    uint4* dst = (uint4*)(kT + (size_t)bh * S_LEN * D_HEAD
                             + (size_t)(bx * 64 + (t >> 2)) * D_HEAD + (t & 3) * 16);
    dst[0] = u.q[0]; dst[1] = u.q[1];
  } else {
    const float* in = vin + (size_t)bh * S_LEN * D_HEAD;
    #pragma unroll
    for (int p = 0; p < 4; ++p) {
      const int row = p * 16 + (t >> 4);
      f32x4 f = ntl4(in + (size_t)(bx * 64 + row) * D_HEAD + (t & 15) * 4);
      tile[row][(t & 15) * 4 + 0] = f.x; tile[row][(t & 15) * 4 + 1] = f.y;
      tile[row][(t & 15) * 4 + 2] = f.z; tile[row][(t & 15) * 4 + 3] = f.w;
    }
    __syncthreads();
    union { unsigned short h[16]; uint4 q[2]; } u;
    #pragma unroll
    for (int i = 0; i < 16; ++i) u.h[i] = (unsigned short)f2bf(tile[(t & 3) * 16 + i][t >> 2]);
    uint4* dst = (uint4*)(vT + (size_t)bh * D_HEAD * S_LEN
                             + (size_t)(t >> 2) * S_LEN + bx * 64 + (t & 3) * 16);
    dst[0] = u.q[0]; dst[1] = u.q[1];
  }
}

// ---------------------------------------------------------------------------
// Fused kernel, wave-private column quarters (wave w owns cols w*512..+512
// for ALL phases -> no cross-wave deps until the sum-reduce):
//  pre : 16-deep prev prefetch (rows it=0,1 of this thread's 4 rows)
//  P1  : QK^T quarter -> LDS (wave-local)          [no barrier]
//  P2  : 32 chunks: consume prev / issue j+16 / scores NT store / e -> LDS;
//        per-row partial sums (4 rows/thread)      [no barrier]
//  PV  : 16 k-steps on own quarter (unnormalized e; A from own-wave LDS)
//  bar ; rl[it] = 1/sum over 4 wave-partials (lred)
//  WST : weights = e*rl NT store (32 chunks, own quarter)
//  bar ; merge 4 waves' partial O via LDS alias, scale, NT store.
// ---------------------------------------------------------------------------
__global__ __launch_bounds__(256, 2) void fused_kernel(
    const float* __restrict__ q, const unsigned short* __restrict__ kT,
    const float* __restrict__ prev, const float* __restrict__ scale_p,
    const unsigned short* __restrict__ vT,
    float* __restrict__ scores, float* __restrict__ weights, float* __restrict__ outO)
{
  __shared__ union {
    unsigned short s[ROWS][SPAD];   // 65664 B
    float om[4][ROWS][68];          // aliased after WST barrier
  } sh;
  __shared__ float lred[4][ROWS];

  const int bh   = blockIdx.y;
  const int m0   = blockIdx.x * ROWS;
  const int tid  = threadIdx.x;
  const int w    = tid >> 6;
  const int lane = tid & 63;
  const int lr   = lane & 15;
  const int lg   = lane >> 4;        // 16-lane group = row group g
  const float scale = scale_p[0];

  // quarter-local P2 mapping: thread serves rows it*4+lg (it=0..3),
  // cols coff + u*64 (u=0..7) within the wave's quarter.
  const int coff = w * 512 + lr * 4;
  const float* pbase = prev    + (size_t)bh * S_LEN * S_LEN + (size_t)m0 * S_LEN + coff;
  float*       sbase = scores  + (size_t)bh * S_LEN * S_LEN + (size_t)m0 * S_LEN + coff;
  float*       wbase = weights + (size_t)bh * S_LEN * S_LEN + (size_t)m0 * S_LEN + coff;

  // ---- deep prefetch: chunks j=0..15 (rows it=0,1) ----
  f32x4 pf[16];
  #pragma unroll
  for (int j = 0; j < 16; ++j)
    pf[j] = ntl4(pbase + (size_t)((j >> 3) * 4 + lg) * S_LEN + (j & 7) * 64);

  // Q A-frags: row = m0+lr, d = kk*32 + lg*8 + j
  short8 aq[2];
  {
    const float* qrow = q + ((size_t)bh * S_LEN + m0 + lr) * D_HEAD;
    #pragma unroll
    for (int kk = 0; kk < 2; ++kk) {
      f32x4 f0 = *(const f32x4*)(qrow + kk * 32 + lg * 8);
      f32x4 f1 = *(const f32x4*)(qrow + kk * 32 + lg * 8 + 4);
      short8 a;
      a[0]=f2bf(f0.x); a[1]=f2bf(f0.y); a[2]=f2bf(f0.z); a[3]=f2bf(f0.w);
      a[4]=f2bf(f1.x); a[5]=f2bf(f1.y); a[6]=f2bf(f1.z); a[7]=f2bf(f1.w);
      aq[kk] = a;
    }
  }

  const unsigned short* kbase = kT + (size_t)bh * S_LEN * D_HEAD;
  const unsigned short* vbase = vT + (size_t)bh * D_HEAD * S_LEN;

  // ---------------- P1: QK^T quarter -> LDS (wave-local) ----------------
  #pragma unroll 2
  for (int t8 = 0; t8 < 8; ++t8) {
    const int n0 = w * 512 + t8 * 64;
    f32x4 acc[4];
    #pragma unroll
    for (int nt = 0; nt < 4; ++nt) acc[nt] = (f32x4){0.f, 0.f, 0.f, 0.f};

    #pragma unroll
    for (int kk = 0; kk < 2; ++kk) {
      #pragma unroll
      for (int nt = 0; nt < 4; ++nt) {
        const short8 b = *(const short8*)(
            kbase + (size_t)(n0 + nt * 16 + lr) * D_HEAD + kk * 32 + lg * 8);
        acc[nt] = __builtin_amdgcn_mfma_f32_16x16x32_bf16(aq[kk], b, acc[nt], 0, 0, 0);
      }
    }
    #pragma unroll
    for (int nt = 0; nt < 4; ++nt)
      #pragma unroll
      for (int rg = 0; rg < 4; ++rg)
        sh.s[lg * 4 + rg][n0 + nt * 16 + lr] = (unsigned short)f2bf(acc[nt][rg]);
  }
  // no barrier: P2 reads only this wave's quarter

  // ---------------- P2: 32 pipelined chunks (own quarter, 4 rows) ---------
  float sums[4] = {0.f, 0.f, 0.f, 0.f};
  #pragma unroll
  for (int j = 0; j < 32; ++j) {
    const int it = j >> 3;
    const int u  = j & 7;
    const int row = it * 4 + lg;
    const f32x4 p = pf[j & 15];
    if (j < 16)
      pf[j & 15] = ntl4(pbase + (size_t)(((j + 16) >> 3) * 4 + lg) * S_LEN + u * 64);
    const int c = coff + u * 64;
    short4v h = *(const short4v*)&sh.s[row][c];
    f32x4 s;
    s.x = bf2f((unsigned short)h[0]) * scale + p.x;
    s.y = bf2f((unsigned short)h[1]) * scale + p.y;
    s.z = bf2f((unsigned short)h[2]) * scale + p.z;
    s.w = bf2f((unsigned short)h[3]) * scale + p.w;
    nts4(sbase + (size_t)row * S_LEN + u * 64, s);
    const float e0 = __expf(s.x), e1 = __expf(s.y), e2 = __expf(s.z), e3 = __expf(s.w);
    sums[it] += (e0 + e1) + (e2 + e3);
    short4v g;
    g[0] = f2bf(e0); g[1] = f2bf(e1); g[2] = f2bf(e2); g[3] = f2bf(e3);
    *(short4v*)&sh.s[row][c] = g;
  }

  // per-row partial sums -> lred[w][row] (16-lane group reduce, same wave)
  #pragma unroll
  for (int it = 0; it < 4; ++it) {
    float s2 = sums[it];
    #pragma unroll
    for (int msk = 1; msk <= 8; msk <<= 1)
      s2 += __shfl_xor(s2, msk, 64);
    if (lr == 0) lred[w][it * 4 + lg] = s2;
  }

  // ---------------- PV on own quarter (unnormalized e) ----------------
  f32x4 accp[4];
  #pragma unroll
  for (int ct = 0; ct < 4; ++ct) accp[ct] = (f32x4){0.f, 0.f, 0.f, 0.f};

  #pragma unroll 2
  for (int i = 0; i < 16; ++i) {
    const int c4 = w * 512 + i * 32 + lg * 8;
    short4v h0 = *(const short4v*)&sh.s[lr][c4];
    short4v h1 = *(const short4v*)&sh.s[lr][c4 + 4];
    short8 a;
    a[0]=h0[0]; a[1]=h0[1]; a[2]=h0[2]; a[3]=h0[3];
    a[4]=h1[0]; a[5]=h1[1]; a[6]=h1[2]; a[7]=h1[3];
    #pragma unroll
    for (int ct = 0; ct < 4; ++ct) {
      const short8 b = *(const short8*)(vbase + (size_t)(ct * 16 + lr) * S_LEN + c4);
      accp[ct] = __builtin_amdgcn_mfma_f32_16x16x32_bf16(a, b, accp[ct], 0, 0, 0);
    }
  }
  __syncthreads();   // lred complete from all waves

  // ---------------- weights = e * rl (own quarter) ----------------
  float rl[4];
  #pragma unroll
  for (int it = 0; it < 4; ++it) {
    const int row = it * 4 + lg;
    rl[it] = 1.0f / (lred[0][row] + lred[1][row] + lred[2][row] + lred[3][row]);
  }
  #pragma unroll
  for (int j = 0; j < 32; ++j) {
    const int it = j >> 3;
    const int u  = j & 7;
    const int row = it * 4 + lg;
    const int c = coff + u * 64;
    short4v hw = *(const short4v*)&sh.s[row][c];
    f32x4 e;
    e.x = bf2f((unsigned short)hw[0]) * rl[it];
    e.y = bf2f((unsigned short)hw[1]) * rl[it];
    e.z = bf2f((unsigned short)hw[2]) * rl[it];
    e.w = bf2f((unsigned short)hw[3]) * rl[it];
    nts4(wbase + (size_t)row * S_LEN + u * 64, e);
  }
  __syncthreads();   // all sh.s reads done; safe to alias sh.om

  #pragma unroll
  for (int ct = 0; ct < 4; ++ct)
    #pragma unroll
    for (int rg = 0; rg < 4; ++rg)
      sh.om[w][lg * 4 + rg][ct * 16 + lr] = accp[ct][rg];
  __syncthreads();

  {
    const int row = tid >> 4;
    const int d4  = (tid & 15) * 4;
    const float rls = 1.0f / (lred[0][row] + lred[1][row] + lred[2][row] + lred[3][row]);
    f32x4 v;
    #pragma unroll
    for (int i = 0; i < 4; ++i)
      v[i] = (sh.om[0][row][d4 + i] + sh.om[1][row][d4 + i]
            + sh.om[2][row][d4 + i] + sh.om[3][row][d4 + i]) * rls;
    nts4(outO + ((size_t)bh * S_LEN + m0 + row) * D_HEAD + d4, v);
  }
}

// ---------------------------------------------------------------------------
extern "C" void kernel_launch(void* const* d_in, const int* in_sizes, int n_in,
                              void* d_out, int out_size, void* d_ws, size_t ws_size,
                              hipStream_t stream)
{
  const float* q     = (const float*)d_in[0];
  const float* kin   = (const float*)d_in[1];
  const float* vin   = (const float*)d_in[2];
  const float* prev  = (const float*)d_in[3];
  const float* scale = (const float*)d_in[4];

  float* O  = (float*)d_out;                                  // [32][2048][64]
  float* W  = O + (size_t)BH * S_LEN * D_HEAD;                // [32][2048][2048]
  float* Sc = W + (size_t)BH * S_LEN * S_LEN;                 // [32][2048][2048]

  unsigned short* kT = (unsigned short*)d_ws;                 // [32][2048][64] bf16
  unsigned short* vT = kT + (size_t)BH * S_LEN * D_HEAD;      // [32][64][2048] bf16

  dim3 tgrid(S_LEN / 64, BH, 2);
  hipLaunchKernelGGL(transpose_kernel, tgrid, dim3(256), 0, stream, kin, vin, kT, vT);

  dim3 grid(S_LEN / ROWS, BH);
  hipLaunchKernelGGL(fused_kernel, grid, dim3(256), 0, stream,
                     q, kT, prev, scale, vT, Sc, W, O);
}

// Round 15
// 417.268 us; speedup vs baseline: 1.0835x; 1.0387x over previous
//
#include <hip/hip_runtime.h>
#include <math.h>

// Problem dims
#define S_LEN 2048
#define D_HEAD 64
#define BH 32
#define ROWS 16

typedef __attribute__((ext_vector_type(8))) short short8;    // 8 bf16 (4 VGPR)
typedef __attribute__((ext_vector_type(4))) short short4v;   // 8B LDS chunk
typedef __attribute__((ext_vector_type(4))) float f32x4;

// LDS row stride in bf16 elems: 4104B rows -> 8B aligned, +2-bank row shift
#define SPAD 2052

__device__ __forceinline__ short f2bf(float f) {
  union { float f; unsigned u; } a; a.f = f;
  unsigned u = a.u;
  unsigned r = (u + 0x7fffu + ((u >> 16) & 1u)) >> 16;   // RNE, no NaNs here
  return (short)r;
}
__device__ __forceinline__ float bf2f(unsigned short h) {
  union { unsigned u; float f; } a; a.u = ((unsigned)h) << 16; return a.f;
}
__device__ __forceinline__ f32x4 ntl4(const float* p) { return __builtin_nontemporal_load((const f32x4*)p); }
__device__ __forceinline__ void  nts4(float* p, f32x4 v) { __builtin_nontemporal_store(v, (f32x4*)p); }

// ---------------------------------------------------------------------------
// Kernel T: K [bh][64][2048] -> kT [bh][2048][64] bf16 ; V [bh][2048][64] ->
// vT [bh][64][2048] bf16. Fully coalesced both sides.
// ---------------------------------------------------------------------------
__global__ __launch_bounds__(256) void transpose_kernel(
    const float* __restrict__ kin, const float* __restrict__ vin,
    unsigned short* __restrict__ kT, unsigned short* __restrict__ vT)
{
  __shared__ float tile[64][65];
  const int bh = blockIdx.y;
  const int bx = blockIdx.x;
  const int t  = threadIdx.x;

  if (blockIdx.z == 0) {
    const float* in = kin + (size_t)bh * D_HEAD * S_LEN;
    #pragma unroll
    for (int p = 0; p < 4; ++p) {
      const int row = p * 16 + (t >> 4);
      f32x4 f = ntl4(in + (size_t)row * S_LEN + bx * 64 + (t & 15) * 4);
      tile[row][(t & 15) * 4 + 0] = f.x; tile[row][(t & 15) * 4 + 1] = f.y;
      tile[row][(t & 15) * 4 + 2] = f.z; tile[row][(t & 15) * 4 + 3] = f.w;
    }
    __syncthreads();
    union { unsigned short h[16]; uint4 q[2]; } u;
    #pragma unroll
    for (int i = 0; i < 16; ++i) u.h[i] = (unsigned short)f2bf(tile[(t & 3) * 16 + i][t >> 2]);
    uint4* dst = (uint4*)(kT + (size_t)bh * S_LEN * D_HEAD
                             + (size_t)(bx * 64 + (t >> 2)) * D_HEAD + (t & 3) * 16);
    dst[0] = u.q[0]; dst[1] = u.q[1];
  } else {
    const float* in = vin + (size_t)bh * S_LEN * D_HEAD;
    #pragma unroll
    for (int p = 0; p < 4; ++p) {
      const int row = p * 16 + (t >> 4);
      f32x4 f = ntl4(in + (size_t)(bx * 64 + row) * D_HEAD + (t & 15) * 4);
      tile[row][(t & 15) * 4 + 0] = f.x; tile[row][(t & 15) * 4 + 1] = f.y;
      tile[row][(t & 15) * 4 + 2] = f.z; tile[row][(t & 15) * 4 + 3] = f.w;
    }
    __syncthreads();
    union { unsigned short h[16]; uint4 q[2]; } u;
    #pragma unroll
    for (int i = 0; i < 16; ++i) u.h[i] = (unsigned short)f2bf(tile[(t & 3) * 16 + i][t >> 2]);
    uint4* dst = (uint4*)(vT + (size_t)bh * D_HEAD * S_LEN
                             + (size_t)(t >> 2) * S_LEN + bx * 64 + (t & 3) * 16);
    dst[0] = u.q[0]; dst[1] = u.q[1];
  }
}

// ---------------------------------------------------------------------------
// Fused kernel = R11 structure, MLP-maximized:
//  pre : ALL 32 prev chunks issued before P1 (128 VGPR, 32 loads in flight)
//  P1  : QK^T MFMA -> bf16(qk) into LDS (C-layout scatter)
//  bar
//  P2  : 32 chunks: consume pf[u], scores NT store, e = exp(s) -> LDS, sum.
//  rl  : 16-lane-group reduce (own wave) -> rl in register
//  WST : weights = e*rl NT store (own row's e, own wave's LDS writes -> no
//        barrier needed; early waves stream stores while others finish P2)
//  bar (e complete for all rows)
//  PV  : 16 k-steps (A = e from LDS, B = vT via L2); stores drain underneath
//  bar ; merge 4 waves' partial O via LDS alias, scale by rl, NT store.
// ---------------------------------------------------------------------------
__global__ __launch_bounds__(256, 2) void fused_kernel(
    const float* __restrict__ q, const unsigned short* __restrict__ kT,
    const float* __restrict__ prev, const float* __restrict__ scale_p,
    const unsigned short* __restrict__ vT,
    float* __restrict__ scores, float* __restrict__ weights, float* __restrict__ outO)
{
  __shared__ union {
    unsigned short s[ROWS][SPAD];   // 65664 B
    float om[4][ROWS][68];          // aliased after PV's LDS reads
  } sh;
  __shared__ float rlv[ROWS];

  const int bh   = blockIdx.y;
  const int m0   = blockIdx.x * ROWS;
  const int tid  = threadIdx.x;
  const int w    = tid >> 6;
  const int lane = tid & 63;
  const int lr   = lane & 15;
  const int lg   = lane >> 4;
  const float scale = scale_p[0];

  // P2 mapping: row owned by an aligned 16-lane group of one wave
  const int row = tid >> 4;          // 0..15
  const int cq  = (tid & 15) * 4;    // 0..60
  const size_t rowoff = (size_t)bh * S_LEN * S_LEN + (size_t)(m0 + row) * S_LEN;
  const float* prevrow = prev + rowoff;

  // ---- maximal prefetch: all 32 chunks of this thread's row ----
  f32x4 pf[32];
  #pragma unroll
  for (int u = 0; u < 32; ++u) pf[u] = ntl4(prevrow + cq + u * 64);

  // Q A-frags: row = m0+lr, d = kk*32 + lg*8 + j
  short8 aq[2];
  {
    const float* qrow = q + ((size_t)bh * S_LEN + m0 + lr) * D_HEAD;
    #pragma unroll
    for (int kk = 0; kk < 2; ++kk) {
      f32x4 f0 = *(const f32x4*)(qrow + kk * 32 + lg * 8);
      f32x4 f1 = *(const f32x4*)(qrow + kk * 32 + lg * 8 + 4);
      short8 a;
      a[0]=f2bf(f0.x); a[1]=f2bf(f0.y); a[2]=f2bf(f0.z); a[3]=f2bf(f0.w);
      a[4]=f2bf(f1.x); a[5]=f2bf(f1.y); a[6]=f2bf(f1.z); a[7]=f2bf(f1.w);
      aq[kk] = a;
    }
  }

  const unsigned short* kbase = kT + (size_t)bh * S_LEN * D_HEAD;

  // ---------------- P1: QK^T -> LDS (bf16 raw products) ----------------
  #pragma unroll 2
  for (int t8 = 0; t8 < 8; ++t8) {
    const int n0 = w * 512 + t8 * 64;
    f32x4 acc[4];
    #pragma unroll
    for (int nt = 0; nt < 4; ++nt) acc[nt] = (f32x4){0.f, 0.f, 0.f, 0.f};

    #pragma unroll
    for (int kk = 0; kk < 2; ++kk) {
      #pragma unroll
      for (int nt = 0; nt < 4; ++nt) {
        const short8 b = *(const short8*)(
            kbase + (size_t)(n0 + nt * 16 + lr) * D_HEAD + kk * 32 + lg * 8);
        acc[nt] = __builtin_amdgcn_mfma_f32_16x16x32_bf16(aq[kk], b, acc[nt], 0, 0, 0);
      }
    }
    #pragma unroll
    for (int nt = 0; nt < 4; ++nt)
      #pragma unroll
      for (int rg = 0; rg < 4; ++rg)
        sh.s[lg * 4 + rg][n0 + nt * 16 + lr] = (unsigned short)f2bf(acc[nt][rg]);
  }
  __syncthreads();

  // ---------------- P2: consume 32 chunks, scores out, e -> LDS -----------
  float* srow = scores + rowoff;
  float sum = 0.f;
  #pragma unroll
  for (int u = 0; u < 32; ++u) {
    const int c = cq + u * 64;
    const f32x4 p = pf[u];
    short4v h = *(const short4v*)&sh.s[row][c];
    f32x4 s;
    s.x = bf2f((unsigned short)h[0]) * scale + p.x;
    s.y = bf2f((unsigned short)h[1]) * scale + p.y;
    s.z = bf2f((unsigned short)h[2]) * scale + p.z;
    s.w = bf2f((unsigned short)h[3]) * scale + p.w;
    nts4(srow + c, s);
    const float e0 = __expf(s.x), e1 = __expf(s.y), e2 = __expf(s.z), e3 = __expf(s.w);
    sum += (e0 + e1) + (e2 + e3);
    short4v g;
    g[0] = f2bf(e0); g[1] = f2bf(e1); g[2] = f2bf(e2); g[3] = f2bf(e3);
    *(short4v*)&sh.s[row][c] = g;
  }

  // row-sum across the 16-lane group (same wave, aligned)
  #pragma unroll
  for (int msk = 1; msk <= 8; msk <<= 1)
    sum += __shfl_xor(sum, msk, 64);
  const float rl = 1.0f / sum;
  if ((tid & 15) == 0) rlv[row] = rl;   // for the epilogue only

  // ---------------- WST: weights = e*rl (own wave's data; pre-barrier) ----
  float* wrow = weights + rowoff;
  #pragma unroll
  for (int u = 0; u < 32; ++u) {
    const int c = cq + u * 64;
    short4v hw = *(const short4v*)&sh.s[row][c];
    f32x4 e;
    e.x = bf2f((unsigned short)hw[0]) * rl;
    e.y = bf2f((unsigned short)hw[1]) * rl;
    e.z = bf2f((unsigned short)hw[2]) * rl;
    e.w = bf2f((unsigned short)hw[3]) * rl;
    nts4(wrow + c, e);
  }
  __syncthreads();   // e in LDS complete for all rows

  // ---------------- PV MFMA (stores drain underneath) ----------------
  const unsigned short* vbase = vT + (size_t)bh * D_HEAD * S_LEN;
  f32x4 accp[4];
  #pragma unroll
  for (int ct = 0; ct < 4; ++ct) accp[ct] = (f32x4){0.f, 0.f, 0.f, 0.f};

  #pragma unroll 2
  for (int i = 0; i < 16; ++i) {
    const int c4 = w * 512 + i * 32 + lg * 8;
    short4v h0 = *(const short4v*)&sh.s[lr][c4];
    short4v h1 = *(const short4v*)&sh.s[lr][c4 + 4];
    short8 a;
    a[0]=h0[0]; a[1]=h0[1]; a[2]=h0[2]; a[3]=h0[3];
    a[4]=h1[0]; a[5]=h1[1]; a[6]=h1[2]; a[7]=h1[3];
    #pragma unroll
    for (int ct = 0; ct < 4; ++ct) {
      const short8 b = *(const short8*)(vbase + (size_t)(ct * 16 + lr) * S_LEN + c4);
      accp[ct] = __builtin_amdgcn_mfma_f32_16x16x32_bf16(a, b, accp[ct], 0, 0, 0);
    }
  }
  __syncthreads();   // all sh.s reads done; safe to alias sh.om

  #pragma unroll
  for (int ct = 0; ct < 4; ++ct)
    #pragma unroll
    for (int rg = 0; rg < 4; ++rg)
      sh.om[w][lg * 4 + rg][ct * 16 + lr] = accp[ct][rg];
  __syncthreads();

  {
    const int d4 = (tid & 15) * 4;
    const float rls = rlv[row];
    f32x4 v;
    #pragma unroll
    for (int i = 0; i < 4; ++i)
      v[i] = (sh.om[0][row][d4 + i] + sh.om[1][row][d4 + i]
            + sh.om[2][row][d4 + i] + sh.om[3][row][d4 + i]) * rls;
    nts4(outO + ((size_t)bh * S_LEN + m0 + row) * D_HEAD + d4, v);
  }
}

// ---------------------------------------------------------------------------
extern "C" void kernel_launch(void* const* d_in, const int* in_sizes, int n_in,
                              void* d_out, int out_size, void* d_ws, size_t ws_size,
                              hipStream_t stream)
{
  const float* q     = (const float*)d_in[0];
  const float* kin   = (const float*)d_in[1];
  const float* vin   = (const float*)d_in[2];
  const float* prev  = (const float*)d_in[3];
  const float* scale = (const float*)d_in[4];

  float* O  = (float*)d_out;                                  // [32][2048][64]
  float* W  = O + (size_t)BH * S_LEN * D_HEAD;                // [32][2048][2048]
  float* Sc = W + (size_t)BH * S_LEN * S_LEN;                 // [32][2048][2048]

  unsigned short* kT = (unsigned short*)d_ws;                 // [32][2048][64] bf16
  unsigned short* vT = kT + (size_t)BH * S_LEN * D_HEAD;      // [32][64][2048] bf16

  dim3 tgrid(S_LEN / 64, BH, 2);
  hipLaunchKernelGGL(transpose_kernel, tgrid, dim3(256), 0, stream, kin, vin, kT, vT);

  dim3 grid(S_LEN / ROWS, BH);
  hipLaunchKernelGGL(fused_kernel, grid, dim3(256), 0, stream,
                     q, kT, prev, scale, vT, Sc, W, O);
}